// Round 11
// baseline (291.969 us; speedup 1.0000x reference)
//
#include <hip/hip_runtime.h>

// Problem constants: B=8, C=64, L=256, D=64, H=4, HD=16
typedef _Float16 f16;
typedef f16   f16x8 __attribute__((ext_vector_type(8)));
typedef float f32x4 __attribute__((ext_vector_type(4)));

#define MFMA(a,b,c) __builtin_amdgcn_mfma_f32_16x16x32_f16(a,b,c,0,0,0)

__device__ __forceinline__ f32x4 fz4(){ f32x4 z; z[0]=0.f; z[1]=0.f; z[2]=0.f; z[3]=0.f; return z; }
__device__ __forceinline__ f16x8 hz8(){ f16x8 z;
#pragma unroll
  for(int i=0;i<8;++i) z[i]=(f16)0.f;
  return z; }

#define NBLK 256u

// Device-scope sense-reversing grid barrier (proven green in r9/r10).
__device__ __forceinline__ void grid_barrier(unsigned* bar) {
  __syncthreads();
  if (threadIdx.x == 0) {
    __threadfence();
    unsigned gen  = atomicAdd(&bar[1], 0u);
    unsigned prev = atomicAdd(&bar[0], 1u);
    if (prev == NBLK - 1u) {
      atomicExch(&bar[0], 0u);
      __threadfence();
      atomicAdd(&bar[1], 1u);
    } else {
      while (atomicAdd(&bar[1], 0u) == gen) __builtin_amdgcn_s_sleep(2);
    }
    __threadfence();
  }
  __syncthreads();
}

// ONE kernel, 256 blocks x 1024 threads (16 waves = 4 waves/SIMD, 1 block/CU
// guaranteed resident): prep -> conv(QKV) -> attention -> proj+LN.
// conv/proj: half-block (8 waves) per tile, 2 tiles in flight.
// attn: whole block per (b,c), each wave owns 16 q-rows.
__global__ __launch_bounds__(1024) void mega(
    const float* __restrict__ query, const float* __restrict__ key,
    const float* __restrict__ value,
    const float* __restrict__ Wq, const float* __restrict__ Wk,
    const float* __restrict__ Wv, const float* __restrict__ Wo,
    const float* __restrict__ bo, const float* __restrict__ gamma,
    const float* __restrict__ beta,
    f16* __restrict__ QKV, f16* __restrict__ AO,
    f16* WA, float* out, unsigned* bar)
{
  __shared__ f16 smem[32768];   // 64 KiB
  const int tid  = threadIdx.x;
  const int bid  = blockIdx.x;
  const int half = tid >> 9;          // half-block id (conv/proj)
  const int ltid = tid & 511;         // tid within half
  const int lane = tid & 63;
  const int wvg  = tid >> 6;          // wave id 0..15 (attn)
  const int wvl  = (ltid >> 6);       // wave id 0..7 within half (conv/proj)
  const int lr   = lane & 15, kh = lane >> 4;
  f16* hs = smem + half*16384;        // 32 KiB per half

  // ================= phase 0: weight prepack =================
  // WA[tensor][kstep(18)][co(64)][kq(4)][j(8)], k=kstep*32+kq*8+j=(ky*3+kx)*64+ci
  // Q weights pre-scaled by 0.25 = 1/sqrt(HD). WA = d_out head (barrier-ordered).
  {
    int gid = bid*1024 + tid;
    if (gid < 110592) {
      int t = gid / 36864, r = gid % 36864;
      const float* W = (t==0)?Wq:((t==1)?Wk:Wv);
      float sc = (t==0) ? 0.25f : 1.0f;
      int kstep = r >> 11, rem = r & 2047;
      int co = rem >> 5, rem2 = rem & 31;
      int kq = rem2 >> 3, j = rem2 & 7;
      int k = kstep*32 + kq*8 + j;
      int sp = k >> 6, ci = k & 63;
      int ky = sp/3, kx = sp - ky*3;
      WA[gid] = (f16)(W[((co*64+ci)*3+ky)*3+kx]*sc);
    }
  }
  grid_barrier(bar);

  // ================= phase 1: conv3x3, half-block per tile, 6 iters ==========
  // w = bid + (iter*2+half)*256: b = w&7 = bid&7 (XCD-local X), t=(w>>3)/128,
  // l0=((w>>3)%128)*2. Tile: 64 co x 128 positions, K=576, 8 waves/tile.
  for (int iter = 0; iter < 6; ++iter) {
    int w    = bid + (iter*2 + half)*256;
    int b    = w & 7;
    int rest = w >> 3;
    int t    = rest >> 7;
    int l0   = (rest & 127) * 2;
    const float* X = (t==0)?query:((t==1)?key:value);
    const f16* WAt = WA + t*36864;
    f16* Yt = QKV + (size_t)t*8388608;
    {
      int ci0 = (ltid & 31)*2;
      int row = (ltid >> 5) & 3;
      int dh  = (ltid >> 7) * 16;      // 4 quarters x 16 d
      int gr  = l0 - 1 + row;
      bool valid = (unsigned)gr < 256u;
      int grc = valid ? gr : 0;
      const f32x4* s0 = (const f32x4*)(X + (((size_t)(b*64+ci0  )*256 + grc)*64 + dh));
      const f32x4* s1 = (const f32x4*)(X + (((size_t)(b*64+ci0+1)*256 + grc)*64 + dh));
#pragma unroll
      for (int q=0;q<4;++q) {
        f32x4 f0 = valid ? s0[q] : fz4();
        f32x4 f1 = valid ? s1[q] : fz4();
#pragma unroll
        for (int e=0;e<4;++e) {
          int d = dh + q*4 + e;
          int idx = ((row*64 + d)*64 + ci0) ^ ((d&7)<<3);   // Xs[row][d][ci]
          unsigned int pk = (unsigned int)__builtin_bit_cast(unsigned short,(f16)f0[e])
                          | ((unsigned int)__builtin_bit_cast(unsigned short,(f16)f1[e]) << 16);
          *(unsigned int*)&hs[idx] = pk;
        }
      }
    }
    __syncthreads();
    f32x4 acc[4];
#pragma unroll
    for (int mt=0;mt<4;++mt) acc[mt]=fz4();
    for (int kstep=0; kstep<18; ++kstep) {
      int sp = kstep >> 1;
      int sp3 = sp/3;
      int dl = sp3 - 1;
      int dd = (sp - sp3*3) - 1;
      int cib = (kstep & 1)*32;
      const f16* wp = WAt + kstep*2048 + lr*32 + kh*8;
      f16x8 a0 = *(const f16x8*)(wp);
      f16x8 a1 = *(const f16x8*)(wp + 512);
      f16x8 a2 = *(const f16x8*)(wp + 1024);
      f16x8 a3 = *(const f16x8*)(wp + 1536);
      f16x8 bb;
      {
        int n = wvl*16 + lr;
        int lloc = n >> 6, d = n & 63;
        int dp = d + dd;
        bool v = (unsigned)dp < 64u;
        int dpc = dp & 63;
        int rowi = lloc + dl + 1;
        int idx = ((rowi*64 + dpc)*64 + cib + kh*8) ^ ((dpc&7)<<3);
        bb = *(const f16x8*)&hs[idx];
        if (!v) bb = hz8();
      }
      acc[0] = MFMA(a0, bb, acc[0]);
      acc[1] = MFMA(a1, bb, acc[1]);
      acc[2] = MFMA(a2, bb, acc[2]);
      acc[3] = MFMA(a3, bb, acc[3]);
    }
#pragma unroll
    for (int mt=0;mt<4;++mt)
#pragma unroll
    for (int r=0;r<4;++r) {
      int co = mt*16 + kh*4 + r;
      int n = wvl*16 + lr;
      int lrow = l0 + (n>>6), d = n & 63;
      Yt[((size_t)(b*64+co)*256 + lrow)*64 + d] = (f16)acc[mt][r];
    }
    __syncthreads();   // smem reused next iteration
  }
  grid_barrier(bar);

  // ================= phase 2: flash attention, whole block per (b,c) =========
  // 2 instances serial; wave owns 16 q-rows. Vt smem[0,16384); P per-wave 1024.
  for (int k2 = 0; k2 < 2; ++k2) {
    int idx = bid + k2*256;
    int bc = (idx & 7)*64 + (idx >> 3);   // batch = bid&7 = producer XCD
    const f16* Qs = QKV + (size_t)bc*16384;
    const f16* Ks = QKV +  8388608 + (size_t)bc*16384;
    const f16* Vs = QKV + 16777216 + (size_t)bc*16384;
    __syncthreads();             // previous instance's readers done
    // V transpose, one pass with 1024 threads: Vt[d][m], idx ^= (d&7)<<3
    {
      int m  = tid & 255;
      int dg = (tid >> 8) * 16;
      f16x8 v0 = *(const f16x8*)(Vs + m*64 + dg);
      f16x8 v1 = *(const f16x8*)(Vs + m*64 + dg + 8);
#pragma unroll
      for (int e=0;e<8;++e){ int d=dg+e;   smem[(d*256+m) ^ ((d&7)<<3)] = v0[e]; }
#pragma unroll
      for (int e=0;e<8;++e){ int d=dg+8+e; smem[(d*256+m) ^ ((d&7)<<3)] = v1[e]; }
    }
    int l0g = wvg*16;
    f16x8 qf[2];
#pragma unroll
    for (int ks=0;ks<2;++ks)
      qf[ks] = *(const f16x8*)(Qs + (l0g + lr)*64 + ks*32 + kh*8);
    f32x4 O[4];
    float rm[4], rl[4];
#pragma unroll
    for (int x=0;x<4;++x) { O[x]=fz4(); rm[x]=-1e30f; rl[x]=0.f; }
    __syncthreads();
    f16* P = &smem[16384 + wvg*1024];   // per-wave private [16 rows][64 m]
    for (int it=0; it<4; ++it) {
      int m0 = it*64;
      f32x4 s[4];
#pragma unroll
      for (int mt=0;mt<4;++mt) s[mt]=fz4();
#pragma unroll
      for (int ks=0;ks<2;++ks) {
        f16x8 kf[4];
#pragma unroll
        for (int mt=0;mt<4;++mt)
          kf[mt] = *(const f16x8*)(Ks + (m0 + mt*16 + lr)*64 + ks*32 + kh*8);
#pragma unroll
        for (int mt=0;mt<4;++mt)
          s[mt] = MFMA(qf[ks], kf[mt], s[mt]);
      }
      // online softmax (scores pre-scaled via Q weights)
#pragma unroll
      for (int r=0;r<4;++r) {
        float tm = fmaxf(fmaxf(s[0][r], s[1][r]), fmaxf(s[2][r], s[3][r]));
#pragma unroll
        for (int off=1; off<16; off<<=1) tm = fmaxf(tm, __shfl_xor(tm, off));
        float mo = rm[r];
        float mn = fmaxf(mo, tm);
        rm[r] = mn;
        float corr = __expf(mo - mn);
        float sum = 0.f;
#pragma unroll
        for (int mt=0;mt<4;++mt) { float p = __expf(s[mt][r] - mn); s[mt][r] = p; sum += p; }
#pragma unroll
        for (int off=1; off<16; off<<=1) sum += __shfl_xor(sum, off);
        rl[r] = rl[r]*corr + sum;
#pragma unroll
        for (int dt=0;dt<4;++dt) O[dt][r] *= corr;
      }
      // P (D-layout) -> wave-private swizzled LDS -> A-layout frags
      // (same-wave DS write->read: in-order — proven r9/r10)
#pragma unroll
      for (int mt=0;mt<4;++mt)
#pragma unroll
      for (int r=0;r<4;++r) {
        int row = kh*4 + r;
        P[(row*64 + mt*16 + lr) ^ ((row&7)<<3)] = (f16)s[mt][r];
      }
#pragma unroll
      for (int ks=0;ks<2;++ks) {
        f16x8 pa, vb[4];
        {
          int row = lr;
          pa = *(const f16x8*)&P[(row*64 + ks*32 + kh*8) ^ ((row&7)<<3)];
        }
#pragma unroll
        for (int dt=0;dt<4;++dt) {
          int d = dt*16 + lr;
          vb[dt] = *(const f16x8*)&smem[(d*256 + m0 + ks*32 + kh*8) ^ ((d&7)<<3)];
        }
#pragma unroll
        for (int dt=0;dt<4;++dt)
          O[dt] = MFMA(pa, vb[dt], O[dt]);
      }
    }
#pragma unroll
    for (int r=0;r<4;++r) {
      float inv = 1.f / rl[r];
      int row = l0g + kh*4 + r;
#pragma unroll
      for (int dt=0;dt<4;++dt)
        AO[(size_t)bc*16384 + row*64 + dt*16 + lr] = (f16)(O[dt][r]*inv);
    }
  }
  grid_barrier(bar);

  // ================= phase 3: 1x1 conv + bias + residual + LN ================
  // half-block (8 waves) per tile, 2 iters: w = bid + (iter*2+half)*256,
  // b = bid&7, p0 = (w>>3)*128. Overwrites ALL of d_out (incl. WA + bar words).
  for (int iter = 0; iter < 2; ++iter) {
    int w  = bid + (iter*2 + half)*256;
    int b  = w & 7;
    int p0 = (w >> 3) * 128;
    {
      int ci = ltid & 63;
      int pg = ltid >> 6;              // 8 groups of 16 positions
      const f16* src = AO + (size_t)(b*64+ci)*16384 + p0 + pg*16;
      f16x8 v0 = *(const f16x8*)(src);
      f16x8 v1 = *(const f16x8*)(src + 8);
#pragma unroll
      for (int e=0;e<8;++e) {
        int p = pg*16 + e;
        hs[(p*64 + ci) ^ ((p&7)<<3)] = v0[e];        // Bt[p][ci] in [0,8192)
      }
#pragma unroll
      for (int e=0;e<8;++e) {
        int p = pg*16 + 8 + e;
        hs[(p*64 + ci) ^ ((p&7)<<3)] = v1[e];
      }
      // Wo fp32 -> f16 into hs[8192..12288): Wos[co][ci], idx ^= (co&7)<<3
      int co  = ltid >> 3;
      int cig = (ltid & 7) * 8;
      const f32x4* wsrc = (const f32x4*)(Wo + co*64 + cig);
      f32x4 w0 = wsrc[0], w1 = wsrc[1];
      f16x8 g0;
#pragma unroll
      for (int e=0;e<4;++e) { g0[e]=(f16)w0[e]; g0[4+e]=(f16)w1[e]; }
      *(f16x8*)&hs[8192 + ((co*64 + cig) ^ ((co&7)<<3))] = g0;
    }
    __syncthreads();
    int n0 = wvl*16;
    f32x4 acc[4];
#pragma unroll
    for (int mt=0;mt<4;++mt) acc[mt]=fz4();
#pragma unroll
    for (int ks=0;ks<2;++ks) {
      f16x8 a[4], bb;
#pragma unroll
      for (int mt=0;mt<4;++mt)
        a[mt] = *(const f16x8*)&hs[8192 + (((mt*16+lr)*64 + ks*32 + kh*8) ^ ((lr&7)<<3))];
      {
        int p = n0 + lr;
        bb = *(const f16x8*)&hs[(p*64 + ks*32 + kh*8) ^ ((p&7)<<3)];
      }
#pragma unroll
      for (int mt=0;mt<4;++mt)
        acc[mt] = MFMA(a[mt], bb, acc[mt]);
    }
    float vals[4][4];
    float sum0=0.f, sq0=0.f;
#pragma unroll
    for (int mt=0;mt<4;++mt)
#pragma unroll
    for (int r=0;r<4;++r) {
      int co = mt*16 + kh*4 + r;
      int p  = p0 + n0 + lr;
      float v = acc[mt][r] + bo[co] + query[(size_t)(b*64+co)*16384 + p];
      vals[mt][r] = v;
      sum0 += v; sq0 += v*v;
    }
#pragma unroll
    for (int off=16; off<64; off<<=1) {
      sum0 += __shfl_xor(sum0, off); sq0 += __shfl_xor(sq0, off);
    }
    float mu0 = sum0*(1.f/64.f), var0 = sq0*(1.f/64.f) - mu0*mu0, rs0 = rsqrtf(var0 + 1e-5f);
#pragma unroll
    for (int mt=0;mt<4;++mt)
#pragma unroll
    for (int r=0;r<4;++r) {
      int co = mt*16 + kh*4 + r;
      int p  = p0 + n0 + lr;
      out[(size_t)(b*64+co)*16384 + p] = (vals[mt][r] - mu0)*rs0*gamma[co] + beta[co];
    }
    __syncthreads();   // smem reused next iteration
  }
}

extern "C" void kernel_launch(void* const* d_in, const int* in_sizes, int n_in,
                              void* d_out, int out_size, void* d_ws, size_t ws_size,
                              hipStream_t stream)
{
  const float* query = (const float*)d_in[0];
  const float* key   = (const float*)d_in[1];
  const float* value = (const float*)d_in[2];
  const float* Wq = (const float*)d_in[3];
  const float* Wk = (const float*)d_in[4];
  const float* Wv = (const float*)d_in[5];
  const float* Wo = (const float*)d_in[6];
  const float* bo = (const float*)d_in[7];
  const float* gamma = (const float*)d_in[8];
  const float* beta  = (const float*)d_in[9];
  char* ws = (char*)d_ws;
  // ws: QKV [0,48MiB) | AO [48,64MiB) — exactly 64 MiB.
  // d_out head: WA (216 KiB) phase-0 scratch; barrier words at +1 MiB
  // (zeroed each call); phase 3 overwrites all of d_out last.
  f16*      QKV  = (f16*)ws;
  f16*      AO   = (f16*)(ws + (size_t)50331648);
  f16*      WA   = (f16*)d_out;
  float*    outp = (float*)d_out;
  unsigned* bar  = (unsigned*)((char*)d_out + (size_t)(1<<20));

  hipMemsetAsync(bar, 0, 64, stream);
  mega<<<dim3(NBLK), dim3(1024), 0, stream>>>(
      query, key, value, Wq, Wk, Wv, Wo, bo, gamma, beta,
      QKV, AO, WA, outp, bar);
}

// Round 12
// 265.936 us; speedup vs baseline: 1.0979x; 1.0979x over previous
//
#include <hip/hip_runtime.h>

// Problem constants: B=8, C=64, L=256, D=64, H=4, HD=16
typedef _Float16 f16;
typedef f16   f16x8 __attribute__((ext_vector_type(8)));
typedef float f32x4 __attribute__((ext_vector_type(4)));

#define MFMA(a,b,c) __builtin_amdgcn_mfma_f32_16x16x32_f16(a,b,c,0,0,0)

__device__ __forceinline__ f32x4 fz4(){ f32x4 z; z[0]=0.f; z[1]=0.f; z[2]=0.f; z[3]=0.f; return z; }
__device__ __forceinline__ f16x8 hz8(){ f16x8 z;
#pragma unroll
  for(int i=0;i<8;++i) z[i]=(f16)0.f;
  return z; }

#define NBLK 256u

// Device-scope sense-reversing grid barrier (r9/r10-proven protocol).
// r12: poll via agent-scope atomic LOAD (no RMW) + longer sleep — the r10/r11
// version hammered one L2 line with RMWs from 255 spinning blocks.
__device__ __forceinline__ void grid_barrier(unsigned* bar) {
  __syncthreads();
  if (threadIdx.x == 0) {
    __threadfence();
    unsigned gen  = __hip_atomic_load(&bar[1], __ATOMIC_RELAXED, __HIP_MEMORY_SCOPE_AGENT);
    unsigned prev = __hip_atomic_fetch_add(&bar[0], 1u, __ATOMIC_ACQ_REL, __HIP_MEMORY_SCOPE_AGENT);
    if (prev == NBLK - 1u) {
      atomicExch(&bar[0], 0u);
      __threadfence();
      __hip_atomic_fetch_add(&bar[1], 1u, __ATOMIC_ACQ_REL, __HIP_MEMORY_SCOPE_AGENT);
    } else {
      while (__hip_atomic_load(&bar[1], __ATOMIC_RELAXED, __HIP_MEMORY_SCOPE_AGENT) == gen)
        __builtin_amdgcn_s_sleep(16);
    }
    __threadfence();
  }
  __syncthreads();
}

// ONE kernel, 256 blocks x 512 threads (r10-proven structure, fastest so far):
// prep -> conv(QKV) -> attention -> proj+LN.
// conv/proj: half-block (4 waves) per tile, 2 tiles in flight.
// attn: whole block per (b,c), each wave owns 32 q-rows.
// r12 delta vs r10: conv kstep loop fully unrolled (compile-time offsets ->
// compiler software-pipelines the 72 weight loads under MFMAs); cheap barrier.
__global__ __launch_bounds__(512, 2) void mega(
    const float* __restrict__ query, const float* __restrict__ key,
    const float* __restrict__ value,
    const float* __restrict__ Wq, const float* __restrict__ Wk,
    const float* __restrict__ Wv, const float* __restrict__ Wo,
    const float* __restrict__ bo, const float* __restrict__ gamma,
    const float* __restrict__ beta,
    f16* __restrict__ QKV, f16* __restrict__ AO,
    f16* WA, float* out, unsigned* bar)
{
  __shared__ f16 smem[32768];   // 64 KiB
  const int tid  = threadIdx.x;
  const int bid  = blockIdx.x;
  const int half = tid >> 8;          // half-block id (conv/proj)
  const int ltid = tid & 255;         // tid within half
  const int lane = tid & 63;
  const int wvg  = tid >> 6;          // wave id 0..7 (attn)
  const int wvl  = (ltid >> 6);       // wave id 0..3 within half (conv/proj)
  const int lr   = lane & 15, kh = lane >> 4;
  f16* hs = smem + half*16384;        // 32 KiB per half

  // ================= phase 0: weight prepack =================
  // WA[tensor][kstep(18)][co(64)][kq(4)][j(8)], k=kstep*32+kq*8+j=(ky*3+kx)*64+ci
  // Q weights pre-scaled by 0.25 = 1/sqrt(HD). WA = d_out head (barrier-ordered).
  {
    int gid = bid*512 + tid;
    if (gid < 110592) {
      int t = gid / 36864, r = gid % 36864;
      const float* W = (t==0)?Wq:((t==1)?Wk:Wv);
      float sc = (t==0) ? 0.25f : 1.0f;
      int kstep = r >> 11, rem = r & 2047;
      int co = rem >> 5, rem2 = rem & 31;
      int kq = rem2 >> 3, j = rem2 & 7;
      int k = kstep*32 + kq*8 + j;
      int sp = k >> 6, ci = k & 63;
      int ky = sp/3, kx = sp - ky*3;
      WA[gid] = (f16)(W[((co*64+ci)*3+ky)*3+kx]*sc);
    }
  }
  grid_barrier(bar);

  // ================= phase 1: conv3x3, half-block per tile, 6 iters ==========
  // w = bid + (iter*2+half)*256: b = w&7 = bid&7 (XCD-local X), t=(w>>3)/128,
  // l0=((w>>3)%128)*2. Tile: 64 co x 128 positions, K=576.
  for (int iter = 0; iter < 6; ++iter) {
    int w    = bid + (iter*2 + half)*256;
    int b    = w & 7;
    int rest = w >> 3;
    int t    = rest >> 7;
    int l0   = (rest & 127) * 2;
    const float* X = (t==0)?query:((t==1)?key:value);
    const f16* WAt = WA + t*36864;
    f16* Yt = QKV + (size_t)t*8388608;
    {
      int ci0 = (ltid & 31)*2;
      int row = (ltid >> 5) & 3;
      int dh  = (ltid >> 7) * 32;
      int gr  = l0 - 1 + row;
      bool valid = (unsigned)gr < 256u;
      int grc = valid ? gr : 0;
      const f32x4* s0 = (const f32x4*)(X + (((size_t)(b*64+ci0  )*256 + grc)*64 + dh));
      const f32x4* s1 = (const f32x4*)(X + (((size_t)(b*64+ci0+1)*256 + grc)*64 + dh));
#pragma unroll
      for (int q=0;q<8;++q) {
        f32x4 f0 = valid ? s0[q] : fz4();
        f32x4 f1 = valid ? s1[q] : fz4();
#pragma unroll
        for (int e=0;e<4;++e) {
          int d = dh + q*4 + e;
          int idx = ((row*64 + d)*64 + ci0) ^ ((d&7)<<3);   // Xs[row][d][ci]
          unsigned int pk = (unsigned int)__builtin_bit_cast(unsigned short,(f16)f0[e])
                          | ((unsigned int)__builtin_bit_cast(unsigned short,(f16)f1[e]) << 16);
          *(unsigned int*)&hs[idx] = pk;
        }
      }
    }
    __syncthreads();
    f32x4 acc[4][2];
#pragma unroll
    for (int mt=0;mt<4;++mt){ acc[mt][0]=fz4(); acc[mt][1]=fz4(); }
#pragma unroll
    for (int kstep=0; kstep<18; ++kstep) {
      int sp = kstep >> 1;             // compile-time after unroll
      int sp3 = sp/3;
      int dl = sp3 - 1;
      int dd = (sp - sp3*3) - 1;
      int cib = (kstep & 1)*32;
      const f16* wp = WAt + kstep*2048 + lr*32 + kh*8;
      f16x8 a0 = *(const f16x8*)(wp);
      f16x8 a1 = *(const f16x8*)(wp + 512);
      f16x8 a2 = *(const f16x8*)(wp + 1024);
      f16x8 a3 = *(const f16x8*)(wp + 1536);
      f16x8 bb[2];
#pragma unroll
      for (int nt=0;nt<2;++nt) {
        int n = wvl*32 + nt*16 + lr;
        int lloc = n >> 6, d = n & 63;
        int dp = d + dd;
        bool v = (unsigned)dp < 64u;
        int dpc = dp & 63;
        int rowi = lloc + dl + 1;
        int idx = ((rowi*64 + dpc)*64 + cib + kh*8) ^ ((dpc&7)<<3);
        f16x8 tt = *(const f16x8*)&hs[idx];
        if (!v) tt = hz8();
        bb[nt] = tt;
      }
#pragma unroll
      for (int nt=0;nt<2;++nt) {
        acc[0][nt] = MFMA(a0, bb[nt], acc[0][nt]);
        acc[1][nt] = MFMA(a1, bb[nt], acc[1][nt]);
        acc[2][nt] = MFMA(a2, bb[nt], acc[2][nt]);
        acc[3][nt] = MFMA(a3, bb[nt], acc[3][nt]);
      }
    }
#pragma unroll
    for (int mt=0;mt<4;++mt)
#pragma unroll
    for (int nt=0;nt<2;++nt)
#pragma unroll
    for (int r=0;r<4;++r) {
      int co = mt*16 + kh*4 + r;
      int n = wvl*32 + nt*16 + lr;
      int lrow = l0 + (n>>6), d = n & 63;
      Yt[((size_t)(b*64+co)*256 + lrow)*64 + d] = (f16)acc[mt][nt][r];
    }
    __syncthreads();   // smem reused next iteration
  }
  grid_barrier(bar);

  // ================= phase 2: flash attention, whole block per (b,c) =========
  // 2 instances serial; wave owns 32 q-rows. Vt smem[0,16384); P per-wave 2048.
  for (int k2 = 0; k2 < 2; ++k2) {
    int idx = bid + k2*256;
    int bc = (idx & 7)*64 + (idx >> 3);   // batch = bid&7 = producer XCD
    const f16* Qs = QKV + (size_t)bc*16384;
    const f16* Ks = QKV +  8388608 + (size_t)bc*16384;
    const f16* Vs = QKV + 16777216 + (size_t)bc*16384;
    __syncthreads();             // previous instance's readers done
    // V transpose: Vt[d][m], idx ^= (d&7)<<3 ; 512 threads
    {
      int m  = tid & 63;
      int dg = (tid >> 6) * 8;   // 8 groups of 8 d
#pragma unroll
      for (int pass=0; pass<4; ++pass) {
        int mm = m + pass*64;
        f16x8 v0 = *(const f16x8*)(Vs + mm*64 + dg);
#pragma unroll
        for (int e=0;e<8;++e){ int d=dg+e; smem[(d*256+mm) ^ ((d&7)<<3)] = v0[e]; }
      }
    }
    int l0g = wvg*32;
    f16x8 qf[2][2];
#pragma unroll
    for (int lt=0;lt<2;++lt)
#pragma unroll
    for (int ks=0;ks<2;++ks)
      qf[lt][ks] = *(const f16x8*)(Qs + (l0g + lt*16 + lr)*64 + ks*32 + kh*8);
    f32x4 O[2][4];
    float rm[2][4], rl[2][4];
#pragma unroll
    for (int lt=0;lt<2;++lt)
#pragma unroll
    for (int x=0;x<4;++x) { O[lt][x]=fz4(); rm[lt][x]=-1e30f; rl[lt][x]=0.f; }
    __syncthreads();
    f16* P = &smem[16384 + wvg*2048];   // per-wave private [32 rows][64 m]
    for (int it=0; it<4; ++it) {
      int m0 = it*64;
      f32x4 s[2][4];
#pragma unroll
      for (int lt=0;lt<2;++lt)
#pragma unroll
      for (int mt=0;mt<4;++mt) s[lt][mt]=fz4();
#pragma unroll
      for (int ks=0;ks<2;++ks) {
        f16x8 kf[4];
#pragma unroll
        for (int mt=0;mt<4;++mt)
          kf[mt] = *(const f16x8*)(Ks + (m0 + mt*16 + lr)*64 + ks*32 + kh*8);
#pragma unroll
        for (int lt=0;lt<2;++lt)
#pragma unroll
        for (int mt=0;mt<4;++mt)
          s[lt][mt] = MFMA(qf[lt][ks], kf[mt], s[lt][mt]);
      }
      // online softmax (scores pre-scaled via Q weights)
#pragma unroll
      for (int lt=0;lt<2;++lt)
#pragma unroll
      for (int r=0;r<4;++r) {
        float tm = fmaxf(fmaxf(s[lt][0][r], s[lt][1][r]), fmaxf(s[lt][2][r], s[lt][3][r]));
#pragma unroll
        for (int off=1; off<16; off<<=1) tm = fmaxf(tm, __shfl_xor(tm, off));
        float mo = rm[lt][r];
        float mn = fmaxf(mo, tm);
        rm[lt][r] = mn;
        float corr = __expf(mo - mn);
        float sum = 0.f;
#pragma unroll
        for (int mt=0;mt<4;++mt) { float p = __expf(s[lt][mt][r] - mn); s[lt][mt][r] = p; sum += p; }
#pragma unroll
        for (int off=1; off<16; off<<=1) sum += __shfl_xor(sum, off);
        rl[lt][r] = rl[lt][r]*corr + sum;
#pragma unroll
        for (int dt=0;dt<4;++dt) O[lt][dt][r] *= corr;
      }
      // P (D-layout) -> wave-private swizzled LDS -> A-layout frags
      // (same-wave DS write->read: in-order — proven r9/r10)
#pragma unroll
      for (int lt=0;lt<2;++lt)
#pragma unroll
      for (int mt=0;mt<4;++mt)
#pragma unroll
      for (int r=0;r<4;++r) {
        int row = lt*16 + kh*4 + r;
        P[(row*64 + mt*16 + lr) ^ ((row&7)<<3)] = (f16)s[lt][mt][r];
      }
#pragma unroll
      for (int ks=0;ks<2;++ks) {
        f16x8 pa[2], vb[4];
#pragma unroll
        for (int lt=0;lt<2;++lt) {
          int row = lt*16 + lr;
          pa[lt] = *(const f16x8*)&P[(row*64 + ks*32 + kh*8) ^ ((row&7)<<3)];
        }
#pragma unroll
        for (int dt=0;dt<4;++dt) {
          int d = dt*16 + lr;
          vb[dt] = *(const f16x8*)&smem[(d*256 + m0 + ks*32 + kh*8) ^ ((d&7)<<3)];
        }
#pragma unroll
        for (int lt=0;lt<2;++lt)
#pragma unroll
        for (int dt=0;dt<4;++dt)
          O[lt][dt] = MFMA(pa[lt], vb[dt], O[lt][dt]);
      }
    }
#pragma unroll
    for (int lt=0;lt<2;++lt)
#pragma unroll
    for (int r=0;r<4;++r) {
      float inv = 1.f / rl[lt][r];
      int row = l0g + lt*16 + kh*4 + r;
#pragma unroll
      for (int dt=0;dt<4;++dt)
        AO[(size_t)bc*16384 + row*64 + dt*16 + lr] = (f16)(O[lt][dt][r]*inv);
    }
  }
  grid_barrier(bar);

  // ================= phase 3: 1x1 conv + bias + residual + LN ================
  // half-block per tile, 2 iters: w = bid + (iter*2+half)*256, b = bid&7,
  // p0 = (w>>3)*128. Overwrites ALL of d_out (incl. WA + barrier words).
  for (int iter = 0; iter < 2; ++iter) {
    int w  = bid + (iter*2 + half)*256;
    int b  = w & 7;
    int p0 = (w >> 3) * 128;
    {
      int ci = ltid & 63;
      int pg = ltid >> 6;
      const f16* src = AO + (size_t)(b*64+ci)*16384 + p0 + pg*32;
      f16x8 v[4];
#pragma unroll
      for (int q=0;q<4;++q) v[q] = *(const f16x8*)(src + q*8);
#pragma unroll
      for (int q=0;q<4;++q)
#pragma unroll
      for (int e=0;e<8;++e) {
        int p = pg*32 + q*8 + e;
        hs[(p*64 + ci) ^ ((p&7)<<3)] = v[q][e];     // Bt[p][ci] in [0,8192)
      }
      // Wo fp32 -> f16 into hs[8192..12288): Wos[co][ci], idx ^= (co&7)<<3
      int co  = ltid >> 2;
      int cig = (ltid & 3) * 16;
      const f32x4* wsrc = (const f32x4*)(Wo + co*64 + cig);
      f32x4 w0 = wsrc[0], w1 = wsrc[1], w2 = wsrc[2], w3 = wsrc[3];
      f16x8 g0, g1;
#pragma unroll
      for (int e=0;e<4;++e) { g0[e]=(f16)w0[e]; g0[4+e]=(f16)w1[e]; g1[e]=(f16)w2[e]; g1[4+e]=(f16)w3[e]; }
      *(f16x8*)&hs[8192 + ((co*64 + cig    ) ^ ((co&7)<<3))] = g0;
      *(f16x8*)&hs[8192 + ((co*64 + cig + 8) ^ ((co&7)<<3))] = g1;
    }
    __syncthreads();
    int n0 = wvl*32;
    f32x4 acc[4][2];
#pragma unroll
    for (int mt=0;mt<4;++mt){ acc[mt][0]=fz4(); acc[mt][1]=fz4(); }
#pragma unroll
    for (int ks=0;ks<2;++ks) {
      f16x8 a[4], bb[2];
#pragma unroll
      for (int mt=0;mt<4;++mt)
        a[mt] = *(const f16x8*)&hs[8192 + (((mt*16+lr)*64 + ks*32 + kh*8) ^ ((lr&7)<<3))];
#pragma unroll
      for (int nt=0;nt<2;++nt) {
        int p = n0 + nt*16 + lr;
        bb[nt] = *(const f16x8*)&hs[(p*64 + ks*32 + kh*8) ^ ((p&7)<<3)];
      }
#pragma unroll
      for (int mt=0;mt<4;++mt)
#pragma unroll
      for (int nt=0;nt<2;++nt)
        acc[mt][nt] = MFMA(a[mt], bb[nt], acc[mt][nt]);
    }
    float vals[4][2][4];
    float sum0=0.f, sq0=0.f, sum1=0.f, sq1=0.f;
#pragma unroll
    for (int mt=0;mt<4;++mt)
#pragma unroll
    for (int nt=0;nt<2;++nt)
#pragma unroll
    for (int r=0;r<4;++r) {
      int co = mt*16 + kh*4 + r;
      int p  = p0 + n0 + nt*16 + lr;
      float v = acc[mt][nt][r] + bo[co] + query[(size_t)(b*64+co)*16384 + p];
      vals[mt][nt][r] = v;
      if (nt==0) { sum0 += v; sq0 += v*v; } else { sum1 += v; sq1 += v*v; }
    }
#pragma unroll
    for (int off=16; off<64; off<<=1) {
      sum0 += __shfl_xor(sum0, off); sq0 += __shfl_xor(sq0, off);
      sum1 += __shfl_xor(sum1, off); sq1 += __shfl_xor(sq1, off);
    }
    float mu0 = sum0*(1.f/64.f), var0 = sq0*(1.f/64.f) - mu0*mu0, rs0 = rsqrtf(var0 + 1e-5f);
    float mu1 = sum1*(1.f/64.f), var1 = sq1*(1.f/64.f) - mu1*mu1, rs1 = rsqrtf(var1 + 1e-5f);
#pragma unroll
    for (int mt=0;mt<4;++mt)
#pragma unroll
    for (int nt=0;nt<2;++nt)
#pragma unroll
    for (int r=0;r<4;++r) {
      int co = mt*16 + kh*4 + r;
      int p  = p0 + n0 + nt*16 + lr;
      float mu = nt ? mu1 : mu0;
      float rs = nt ? rs1 : rs0;
      out[(size_t)(b*64+co)*16384 + p] = (vals[mt][nt][r] - mu)*rs*gamma[co] + beta[co];
    }
    __syncthreads();   // smem reused next iteration
  }
}

extern "C" void kernel_launch(void* const* d_in, const int* in_sizes, int n_in,
                              void* d_out, int out_size, void* d_ws, size_t ws_size,
                              hipStream_t stream)
{
  const float* query = (const float*)d_in[0];
  const float* key   = (const float*)d_in[1];
  const float* value = (const float*)d_in[2];
  const float* Wq = (const float*)d_in[3];
  const float* Wk = (const float*)d_in[4];
  const float* Wv = (const float*)d_in[5];
  const float* Wo = (const float*)d_in[6];
  const float* bo = (const float*)d_in[7];
  const float* gamma = (const float*)d_in[8];
  const float* beta  = (const float*)d_in[9];
  char* ws = (char*)d_ws;
  // ws: QKV [0,48MiB) | AO [48,64MiB) — exactly 64 MiB.
  // d_out head: WA (216 KiB) phase-0 scratch; barrier words at +1 MiB
  // (zeroed each call); phase 3 overwrites all of d_out last.
  f16*      QKV  = (f16*)ws;
  f16*      AO   = (f16*)(ws + (size_t)50331648);
  f16*      WA   = (f16*)d_out;
  float*    outp = (float*)d_out;
  unsigned* bar  = (unsigned*)((char*)d_out + (size_t)(1<<20));

  hipMemsetAsync(bar, 0, 64, stream);
  mega<<<dim3(NBLK), dim3(512), 0, stream>>>(
      query, key, value, Wq, Wk, Wv, Wo, bo, gamma, beta,
      QKV, AO, WA, outp, bar);
}